// Round 1
// baseline (178.827 us; speedup 1.0000x reference)
//
#include <hip/hip_runtime.h>
#include <hip/hip_bf16.h>

// V[k,d] = sum_n a_bar[k,n]*x[d,n] - c[k,d]*sum_n a_bar[k,n]
// K=64 (rows), D=512 (cols), N=131072 (reduction)
// Stage 1: split-N MFMA GEMM (bf16 inputs, fp32 accum) -> partials in d_ws
// Stage 2: reduce partials + fused c*a_sum epilogue.

#define K_ROWS 64
#define D_COLS 512
#define N_RED  131072LL

typedef __attribute__((ext_vector_type(8))) short short8;
typedef __attribute__((ext_vector_type(4))) float f32x4;

__device__ __forceinline__ short f2bf(float f) {
    __bf16 h = (__bf16)f;                  // RNE fptrunc; compiler emits v_cvt_pk_bf16_f32
    return __builtin_bit_cast(short, h);
}

__device__ __forceinline__ short8 cvt8(float4 a, float4 b) {
    short8 r;
    r[0] = f2bf(a.x); r[1] = f2bf(a.y); r[2] = f2bf(a.z); r[3] = f2bf(a.w);
    r[4] = f2bf(b.x); r[5] = f2bf(b.y); r[6] = f2bf(b.z); r[7] = f2bf(b.w);
    return r;
}

// Grid: 8 * S blocks of 256 threads (4 waves).
// Block (g, s): d-range [g*64, g*64+64), n-range [s*chunk, (s+1)*chunk).
// Wave w owns d-subtile [g*64 + w*16, +16), all 64 k-rows (4 m-tiles of 16).
// mfma_f32_16x16x32_bf16 fragments: lane l holds 8 contiguous reduction elems
// at row/col (l&15), k-group (l>>4)*8. C/D: col = l&15, row = (l>>4)*4 + reg.
__global__ __launch_bounds__(256, 2) void vlad_stage1(
    const float* __restrict__ x, const float* __restrict__ ab,
    float* __restrict__ pax, float* __restrict__ pasum, int chunk)
{
    const int g  = blockIdx.x & 7;
    const int s  = blockIdx.x >> 3;
    const int w  = threadIdx.x >> 6;
    const int l  = threadIdx.x & 63;
    const int lr = l & 15;
    const int lg = l >> 4;

    const long long n0 = (long long)s * chunk + lg * 8;
    const float* xp = x  + (size_t)(g * 64 + w * 16 + lr) * N_RED + n0;
    const float* ap = ab + (size_t)lr * N_RED + n0;

    f32x4 acc[4] = {};
    float asum = 0.f;
    const bool g0 = (g == 0);

    const int steps = chunk >> 5;
    #pragma unroll 2
    for (int it = 0; it < steps; ++it) {
        float4 b0 = *(const float4*)(xp);
        float4 b1 = *(const float4*)(xp + 4);
        short8 bfrag = cvt8(b0, b1);
        #pragma unroll
        for (int t = 0; t < 4; ++t) {
            const float* apt = ap + (size_t)t * 16 * N_RED;
            float4 a0 = *(const float4*)(apt);
            float4 a1 = *(const float4*)(apt + 4);
            if (g0 && w == t) {   // wave-uniform; spread a_sum work across waves
                asum += ((a0.x + a0.y) + (a0.z + a0.w))
                      + ((a1.x + a1.y) + (a1.z + a1.w));
            }
            short8 afrag = cvt8(a0, a1);
            acc[t] = __builtin_amdgcn_mfma_f32_16x16x32_bf16(afrag, bfrag, acc[t], 0, 0, 0);
        }
        xp += 32; ap += 32;
    }

    // Partial ax tile -> pax[s][row][col], col = g*64 + w*16 + lr
    float* dst = pax + (size_t)s * (K_ROWS * D_COLS) + (g * 64 + w * 16 + lr);
    #pragma unroll
    for (int t = 0; t < 4; ++t)
        #pragma unroll
        for (int r = 0; r < 4; ++r)
            dst[(size_t)(t * 16 + lg * 4 + r) * D_COLS] = acc[t][r];

    // Partial a_sum: wave w accumulated rows [w*16, w*16+16) over lg groups.
    asum += __shfl_xor(asum, 16, 64);
    asum += __shfl_xor(asum, 32, 64);
    if (g0 && l < 16) pasum[s * K_ROWS + w * 16 + l] = asum;
}

// Grid: (K*D)/64 = 512 blocks of 256 threads. Each block: 64 outputs,
// 4-way split over s (one wave per split), LDS combine, fused epilogue.
__global__ __launch_bounds__(256) void vlad_stage2(
    const float* __restrict__ pax, const float* __restrict__ pasum,
    const float* __restrict__ c, float* __restrict__ out, int S)
{
    __shared__ float red[256];
    const int t  = threadIdx.x;
    const int o  = blockIdx.x * 64 + (t & 63);
    const int sp = t >> 6;

    float acc = 0.f;
    for (int s = sp; s < S; s += 4)
        acc += pax[(size_t)s * (K_ROWS * D_COLS) + o];
    red[t] = acc;
    __syncthreads();

    if (sp == 0) {
        const int k = o >> 9;
        float asum = 0.f;
        for (int s = 0; s < S; ++s) asum += pasum[s * K_ROWS + k];
        float v = red[t] + red[t + 64] + red[t + 128] + red[t + 192];
        out[o] = v - c[o] * asum;
    }
}

extern "C" void kernel_launch(void* const* d_in, const int* in_sizes, int n_in,
                              void* d_out, int out_size, void* d_ws, size_t ws_size,
                              hipStream_t stream)
{
    const float* x  = (const float*)d_in[0];
    const float* ab = (const float*)d_in[1];
    const float* c  = (const float*)d_in[2];
    float* out = (float*)d_out;

    // Pick largest S (power of 2, <= 64) whose partials fit in d_ws.
    int S = 64;
    while (S > 1 &&
           (size_t)S * (size_t)(K_ROWS * D_COLS + K_ROWS) * sizeof(float) > ws_size)
        S >>= 1;
    const int chunk = (int)(N_RED / S);

    float* pax   = (float*)d_ws;
    float* pasum = pax + (size_t)S * K_ROWS * D_COLS;

    vlad_stage1<<<dim3(8 * S), dim3(256), 0, stream>>>(x, ab, pax, pasum, chunk);
    vlad_stage2<<<dim3((K_ROWS * D_COLS) / 64), dim3(256), 0, stream>>>(pax, pasum, c, out, S);
}

// Round 2
// 157.403 us; speedup vs baseline: 1.1361x; 1.1361x over previous
//
#include <hip/hip_runtime.h>
#include <hip/hip_bf16.h>

// V[k,d] = sum_n a_bar[k,n]*x[d,n] - c[k,d]*sum_n a_bar[k,n]
// K=64, D=512, N=131072.
// Stage 1: split-N MFMA GEMM (bf16 inputs, fp32 accum) -> partials in d_ws.
//   512-thread blocks (8 waves): 4 d-tiles x 2 n-halves, LDS combine.
//   Explicit register double-buffer: 10 dwordx4 loads in flight per wave.
// Stage 2: reduce partials + fused c*a_sum epilogue.

#define K_ROWS 64
#define D_COLS 512
#define N_RED  131072LL

typedef __attribute__((ext_vector_type(8))) short short8;
typedef __attribute__((ext_vector_type(4))) float f32x4;

__device__ __forceinline__ short f2bf(float f) {
    __bf16 h = (__bf16)f;                  // RNE; pairs fuse to v_cvt_pk_bf16_f32
    return __builtin_bit_cast(short, h);
}

__device__ __forceinline__ short8 cvt8(float4 a, float4 b) {
    short8 r;
    r[0] = f2bf(a.x); r[1] = f2bf(a.y); r[2] = f2bf(a.z); r[3] = f2bf(a.w);
    r[4] = f2bf(b.x); r[5] = f2bf(b.y); r[6] = f2bf(b.z); r[7] = f2bf(b.w);
    return r;
}

// Grid: 8*S blocks of 512 threads (8 waves).
// Block (g,s): d-cols [g*64, g*64+64), n-chunk s.
// Wave w: d-subtile tt=(w&3) (16 cols), n-half h=(w>>2). All 64 k-rows (4 m-tiles).
// mfma_f32_16x16x32_bf16: lane l holds 8 contiguous n-elems at row/col (l&15),
// n-group (l>>4)*8. C/D: col=l&15, row=(l>>4)*4+reg.
__global__ __launch_bounds__(512, 1) void vlad_stage1(
    const float* __restrict__ x, const float* __restrict__ ab,
    float* __restrict__ pax, float* __restrict__ pasum, int chunk)
{
    __shared__ float red[4 * 16 * 64];   // 16 KB: h==1 waves' accumulators

    const int g  = blockIdx.x & 7;
    const int s  = blockIdx.x >> 3;
    const int w  = threadIdx.x >> 6;
    const int l  = threadIdx.x & 63;
    const int tt = w & 3;
    const int h  = w >> 2;
    const int lr = l & 15;
    const int lg = l >> 4;

    const int half  = chunk >> 1;
    const int steps = half >> 5;          // 32-wide k-steps per wave
    const long long n0 = (long long)s * chunk + (long long)h * half + lg * 8;
    const float* xp = x  + (size_t)(g * 64 + tt * 16 + lr) * N_RED + n0;
    const float* ap = ab + (size_t)lr * N_RED + n0;
    const bool g0 = (g == 0);

    f32x4 acc[4] = {};
    float asum = 0.f;

    // --- prologue: fill current register buffer (10 x dwordx4) ---
    float4 cx0 = *(const float4*)(xp);
    float4 cx1 = *(const float4*)(xp + 4);
    float4 ca0[4], ca1[4];
    #pragma unroll
    for (int t = 0; t < 4; ++t) {
        const float* p = ap + (size_t)t * 16 * N_RED;
        ca0[t] = *(const float4*)(p);
        ca1[t] = *(const float4*)(p + 4);
    }

    #pragma unroll 1
    for (int it = 0; it < steps - 1; ++it) {
        // issue next iteration's 10 loads before touching current values
        xp += 32; ap += 32;
        float4 nx0 = *(const float4*)(xp);
        float4 nx1 = *(const float4*)(xp + 4);
        float4 na0[4], na1[4];
        #pragma unroll
        for (int t = 0; t < 4; ++t) {
            const float* p = ap + (size_t)t * 16 * N_RED;
            na0[t] = *(const float4*)(p);
            na1[t] = *(const float4*)(p + 4);
        }

        // compute on current buffer (waits only on loads issued last iter)
        short8 bfrag = cvt8(cx0, cx1);
        #pragma unroll
        for (int t = 0; t < 4; ++t) {
            if (g0 && t == tt) {   // wave-uniform: spread a_sum across waves
                asum += ((ca0[t].x + ca0[t].y) + (ca0[t].z + ca0[t].w))
                      + ((ca1[t].x + ca1[t].y) + (ca1[t].z + ca1[t].w));
            }
            acc[t] = __builtin_amdgcn_mfma_f32_16x16x32_bf16(
                         cvt8(ca0[t], ca1[t]), bfrag, acc[t], 0, 0, 0);
        }

        cx0 = nx0; cx1 = nx1;
        #pragma unroll
        for (int t = 0; t < 4; ++t) { ca0[t] = na0[t]; ca1[t] = na1[t]; }
    }

    // --- epilogue: last step ---
    {
        short8 bfrag = cvt8(cx0, cx1);
        #pragma unroll
        for (int t = 0; t < 4; ++t) {
            if (g0 && t == tt) {
                asum += ((ca0[t].x + ca0[t].y) + (ca0[t].z + ca0[t].w))
                      + ((ca1[t].x + ca1[t].y) + (ca1[t].z + ca1[t].w));
            }
            acc[t] = __builtin_amdgcn_mfma_f32_16x16x32_bf16(
                         cvt8(ca0[t], ca1[t]), bfrag, acc[t], 0, 0, 0);
        }
    }

    // --- combine the two n-halves via LDS, h==0 waves write the partial ---
    if (h == 1) {
        #pragma unroll
        for (int t = 0; t < 4; ++t)
            #pragma unroll
            for (int r = 0; r < 4; ++r)
                red[tt * 1024 + (t * 4 + r) * 64 + l] = acc[t][r];
    }
    __syncthreads();
    if (h == 0) {
        float* dst = pax + (size_t)s * (K_ROWS * D_COLS) + (g * 64 + tt * 16 + lr);
        #pragma unroll
        for (int t = 0; t < 4; ++t)
            #pragma unroll
            for (int r = 0; r < 4; ++r) {
                float v = acc[t][r] + red[tt * 1024 + (t * 4 + r) * 64 + l];
                dst[(size_t)(t * 16 + lg * 4 + r) * D_COLS] = v;
            }
    }

    // --- a_sum partial: wave handled rows tt*16+lr over lg n-groups ---
    asum += __shfl_xor(asum, 16, 64);
    asum += __shfl_xor(asum, 32, 64);
    if (g0 && l < 16)
        pasum[(s * 2 + h) * K_ROWS + tt * 16 + l] = asum;
}

// Grid: (K*D)/64 = 512 blocks of 256. Block b: 64 outputs (single k = b>>3),
// 4-way s-split + LDS combine; block-parallel a_sum reduce.
__global__ __launch_bounds__(256) void vlad_stage2(
    const float* __restrict__ pax, const float* __restrict__ pasum,
    const float* __restrict__ c, float* __restrict__ out, int S)
{
    __shared__ float red[256];
    __shared__ float ared[256];
    const int t  = threadIdx.x;
    const int o  = blockIdx.x * 64 + (t & 63);
    const int sp = t >> 6;
    const int k  = blockIdx.x >> 3;   // D_COLS/64 = 8 blocks per k-row

    float pa = 0.f;
    for (int e = t; e < 2 * S; e += 256) pa += pasum[e * K_ROWS + k];
    ared[t] = pa;

    float acc = 0.f;
    for (int s = sp; s < S; s += 4)
        acc += pax[(size_t)s * (K_ROWS * D_COLS) + o];
    red[t] = acc;
    __syncthreads();

    for (int st = 128; st > 0; st >>= 1) {
        if (t < st) ared[t] += ared[t + st];
        __syncthreads();
    }
    if (sp == 0) {
        float v = red[t] + red[t + 64] + red[t + 128] + red[t + 192];
        out[o] = v - c[o] * ared[0];
    }
}

extern "C" void kernel_launch(void* const* d_in, const int* in_sizes, int n_in,
                              void* d_out, int out_size, void* d_ws, size_t ws_size,
                              hipStream_t stream)
{
    const float* x  = (const float*)d_in[0];
    const float* ab = (const float*)d_in[1];
    const float* c  = (const float*)d_in[2];
    float* out = (float*)d_out;

    // S = 64 known to fit from round 1 (8.4 MB); halve defensively if not.
    int S = 64;
    while (S > 1 &&
           (size_t)S * (size_t)(K_ROWS * D_COLS + 2 * K_ROWS) * sizeof(float) > ws_size)
        S >>= 1;
    const int chunk = (int)(N_RED / S);

    float* pax   = (float*)d_ws;
    float* pasum = pax + (size_t)S * K_ROWS * D_COLS;

    vlad_stage1<<<dim3(8 * S), dim3(512), 0, stream>>>(x, ab, pax, pasum, chunk);
    vlad_stage2<<<dim3((K_ROWS * D_COLS) / 64), dim3(256), 0, stream>>>(pax, pasum, c, out, S);
}

// Round 3
// 81.800 us; speedup vs baseline: 2.1861x; 1.9242x over previous
//
#include <hip/hip_runtime.h>
#include <hip/hip_bf16.h>

// V[k,d] = sum_n a_bar[k,n]*x[d,n] - c[k,d]*sum_n a_bar[k,n]
// K=64, D=512, N=131072.
// Stage 1: LDS-staged split-N MFMA GEMM (global_load_lds, XOR-swizzled tiles,
//          bf16 MFMA, fp32 accum) -> partials in d_ws.
// Stage 2: reduce partials + fused c*a_sum epilogue.

#define K_ROWS 64
#define D_COLS 512
#define N_RED  131072LL

#define DT     256           // d-cols per block (2 col-blocks cover D=512)
#define BK     32            // n-elements per K-step
#define XBYTES (DT * BK * 4) // 32 KB x-tile
#define ABYTES (K_ROWS * BK * 4) // 8 KB a-tile
#define BUFB   (XBYTES + ABYTES) // 40 KB per buffer

typedef __attribute__((ext_vector_type(8))) short short8;
typedef __attribute__((ext_vector_type(4))) float f32x4;

__device__ __forceinline__ short f2bf(float f) {
    __bf16 h = (__bf16)f;                  // RNE; pairs fuse to v_cvt_pk_bf16_f32
    return __builtin_bit_cast(short, h);
}

__device__ __forceinline__ short8 cvt8(float4 a, float4 b) {
    short8 r;
    r[0] = f2bf(a.x); r[1] = f2bf(a.y); r[2] = f2bf(a.z); r[3] = f2bf(a.w);
    r[4] = f2bf(b.x); r[5] = f2bf(b.y); r[6] = f2bf(b.z); r[7] = f2bf(b.w);
    return r;
}

__device__ __forceinline__ void gload_lds16(const float* g, char* l) {
    __builtin_amdgcn_global_load_lds(
        (const __attribute__((address_space(1))) void*)g,
        (__attribute__((address_space(3))) void*)l, 16, 0, 0);
}

// Stage one (x-tile, a-tile) pair for n-window [noff, noff+32) into lbase.
// LDS unit u (16B) holds tile element (row = u>>3, col-unit (u&7)^(row&7)) —
// XOR swizzle baked in via the per-lane GLOBAL source address; LDS dest is
// linear (global_load_lds requirement). Each row's 8 units come from the same
// contiguous 128B global segment, so loads stay fully coalesced.
__device__ __forceinline__ void stage_tiles(
    const float* __restrict__ x, const float* __restrict__ ab,
    char* lbase, int d0, size_t noff, int tid)
{
    const int wb = tid & ~63;          // wave-uniform LDS unit base
    #pragma unroll
    for (int r = 0; r < 4; ++r) {      // x: 2048 units = 4 rounds x 512 thr
        int u   = r * 512 + tid;
        int row = u >> 3;
        int un  = (u & 7) ^ (row & 7);
        const float* g = x + (size_t)(d0 + row) * N_RED + noff + un * 4;
        gload_lds16(g, lbase + (size_t)(r * 512 + wb) * 16);
    }
    {                                  // a: 512 units = 1 round
        int row = tid >> 3;
        int un  = (tid & 7) ^ (row & 7);
        const float* g = ab + (size_t)row * N_RED + noff + un * 4;
        gload_lds16(g, lbase + XBYTES + (size_t)wb * 16);
    }
}

// Grid: 2*S blocks of 512 threads (8 waves). Block (g,s): d-cols [g*256,+256),
// n-chunk s. Wave w owns d-cols [g*256+w*32, +32) x all 64 k-rows.
// mfma_f32_16x16x32_bf16: lane l holds 8 contiguous n at row/col (l&15),
// n-group (l>>4)*8. C/D: col=l&15, row=(l>>4)*4+reg.
__global__ __launch_bounds__(512, 4) void vlad_stage1(
    const float* __restrict__ x, const float* __restrict__ ab,
    float* __restrict__ pax, float* __restrict__ pasum, int chunk)
{
    extern __shared__ char smem[];     // 2 * BUFB = 80 KB
    const int g   = blockIdx.x & 1;
    const int s   = blockIdx.x >> 1;
    const int tid = threadIdx.x;
    const int w   = tid >> 6;
    const int l   = tid & 63;
    const int lr  = l & 15;
    const int lg  = l >> 4;
    const int d0  = g * DT;
    const size_t nblk = (size_t)s * chunk;
    const int steps   = chunk >> 5;
    const int swz     = lr & 7;

    // Fragment read offsets (bytes) — swizzle matches stage_tiles.
    int offx[2][2], offa[4][2];
    #pragma unroll
    for (int sub = 0; sub < 2; ++sub) {
        int xrow = w * 32 + sub * 16 + lr;
        #pragma unroll
        for (int c = 0; c < 2; ++c)
            offx[sub][c] = (xrow * 8 + ((lg * 2 + c) ^ swz)) * 16;
    }
    #pragma unroll
    for (int t = 0; t < 4; ++t) {
        int arow = t * 16 + lr;
        #pragma unroll
        for (int c = 0; c < 2; ++c)
            offa[t][c] = XBYTES + (arow * 8 + ((lg * 2 + c) ^ swz)) * 16;
    }

    f32x4 acc[4][2] = {};
    float asum[4] = {0.f, 0.f, 0.f, 0.f};
    const bool do_asum = (g == 0) && (w == 0);

    stage_tiles(x, ab, smem, d0, nblk, tid);

    int cur = 0;
    #pragma unroll 1
    for (int it = 0; it < steps; ++it) {
        // Barrier: compiler-inserted vmcnt(0) drains buf[cur] staging;
        // lgkmcnt(0) drains last iter's ds_reads of buf[cur^1] before we
        // overwrite it below.
        __syncthreads();
        if (it + 1 < steps)
            stage_tiles(x, ab, smem + (cur ^ 1) * BUFB, d0,
                        nblk + (size_t)(it + 1) * BK, tid);

        char* b = smem + cur * BUFB;
        float4 a0[4], a1[4];
        #pragma unroll
        for (int t = 0; t < 4; ++t) {
            a0[t] = *(const float4*)(b + offa[t][0]);
            a1[t] = *(const float4*)(b + offa[t][1]);
        }
        float4 x0[2], x1[2];
        #pragma unroll
        for (int sub = 0; sub < 2; ++sub) {
            x0[sub] = *(const float4*)(b + offx[sub][0]);
            x1[sub] = *(const float4*)(b + offx[sub][1]);
        }
        if (do_asum) {
            #pragma unroll
            for (int t = 0; t < 4; ++t)
                asum[t] += ((a0[t].x + a0[t].y) + (a0[t].z + a0[t].w))
                         + ((a1[t].x + a1[t].y) + (a1[t].z + a1[t].w));
        }
        short8 xb0 = cvt8(x0[0], x1[0]);
        short8 xb1 = cvt8(x0[1], x1[1]);
        #pragma unroll
        for (int t = 0; t < 4; ++t) {
            short8 ab8 = cvt8(a0[t], a1[t]);
            acc[t][0] = __builtin_amdgcn_mfma_f32_16x16x32_bf16(ab8, xb0, acc[t][0], 0, 0, 0);
            acc[t][1] = __builtin_amdgcn_mfma_f32_16x16x32_bf16(ab8, xb1, acc[t][1], 0, 0, 0);
        }
        cur ^= 1;
    }

    // Partial tile -> pax[s][k][d]
    float* dst = pax + (size_t)s * (K_ROWS * D_COLS);
    #pragma unroll
    for (int t = 0; t < 4; ++t)
        #pragma unroll
        for (int sub = 0; sub < 2; ++sub)
            #pragma unroll
            for (int r = 0; r < 4; ++r)
                dst[(size_t)(t * 16 + lg * 4 + r) * D_COLS
                    + d0 + w * 32 + sub * 16 + lr] = acc[t][sub][r];

    if (do_asum) {
        #pragma unroll
        for (int t = 0; t < 4; ++t) {
            asum[t] += __shfl_xor(asum[t], 16, 64);
            asum[t] += __shfl_xor(asum[t], 32, 64);
        }
        if (l < 16)
            #pragma unroll
            for (int t = 0; t < 4; ++t)
                pasum[s * K_ROWS + t * 16 + l] = asum[t];
    }
}

// Grid: (K*D)/64 = 512 blocks of 256. Block b: 64 outputs (k = b>>3),
// 4-way s-split + LDS combine; block-parallel a_sum reduce.
__global__ __launch_bounds__(256) void vlad_stage2(
    const float* __restrict__ pax, const float* __restrict__ pasum,
    const float* __restrict__ c, float* __restrict__ out, int S)
{
    __shared__ float red[256];
    __shared__ float ared[256];
    const int t  = threadIdx.x;
    const int o  = blockIdx.x * 64 + (t & 63);
    const int sp = t >> 6;
    const int k  = blockIdx.x >> 3;   // D_COLS/64 = 8 blocks per k-row

    float pa = 0.f;
    for (int e = t; e < S; e += 256) pa += pasum[e * K_ROWS + k];
    ared[t] = pa;

    float acc = 0.f;
    for (int s = sp; s < S; s += 4)
        acc += pax[(size_t)s * (K_ROWS * D_COLS) + o];
    red[t] = acc;
    __syncthreads();

    for (int st = 128; st > 0; st >>= 1) {
        if (t < st) ared[t] += ared[t + st];
        __syncthreads();
    }
    if (sp == 0) {
        float v = red[t] + red[t + 64] + red[t + 128] + red[t + 192];
        out[o] = v - c[o] * ared[0];
    }
}

extern "C" void kernel_launch(void* const* d_in, const int* in_sizes, int n_in,
                              void* d_out, int out_size, void* d_ws, size_t ws_size,
                              hipStream_t stream)
{
    const float* x  = (const float*)d_in[0];
    const float* ab = (const float*)d_in[1];
    const float* c  = (const float*)d_in[2];
    float* out = (float*)d_out;

    // Largest power-of-2 S whose partials fit in d_ws (S=64 known to fit).
    int S = 256;
    while (S > 4 &&
           (size_t)S * (size_t)(K_ROWS * D_COLS + K_ROWS) * sizeof(float) > ws_size)
        S >>= 1;
    const int chunk = (int)(N_RED / S);

    float* pax   = (float*)d_ws;
    float* pasum = pax + (size_t)S * K_ROWS * D_COLS;

    vlad_stage1<<<dim3(2 * S), dim3(512), 2 * BUFB, stream>>>(x, ab, pax, pasum, chunk);
    vlad_stage2<<<dim3((K_ROWS * D_COLS) / 64), dim3(256), 0, stream>>>(pax, pasum, c, out, S);
}